// Round 3
// baseline (3821.431 us; speedup 1.0000x reference)
//
#include <hip/hip_runtime.h>
#include <stdint.h>
#include <math.h>

#define NB 64
#define NT 512
#define NF 128
#define NH 512
#define NO 128

typedef short  s16x8  __attribute__((ext_vector_type(8)));   // 8 bf16
typedef float  f32x4  __attribute__((ext_vector_type(4)));   // 16x16 acc
typedef float  f32x16 __attribute__((ext_vector_type(16)));  // 32x32 acc (head)

// ---------------- workspace layout (bytes) ----------------
#define OFF_XBF   ((size_t)0)                      // B*T*F bf16 = 8 MB
#define OFF_WOUT  ((size_t)(8u<<20))               // O*H bf16 = 128 KB
#define OFF_SEQ0  ((size_t)(12u<<20))              // B*T*H bf16 = 32 MB
#define OFF_SEQ1  (OFF_SEQ0 + ((size_t)32u<<20))
#define OFF_SEQ2  (OFF_SEQ1 + ((size_t)32u<<20))
#define OFF_FLAGS (OFF_SEQ2 + ((size_t)32u<<20))   // 12 counters, 64B apart

__device__ __forceinline__ unsigned short f2bf(float f) {
  unsigned int u = __float_as_uint(f);
  u += 0x7fffu + ((u >> 16) & 1u);   // RNE
  return (unsigned short)(u >> 16);
}

// relaxed agent poll (no cache inv); want==0 -> no-op. Divergent-safe.
__device__ __forceinline__ void waitge(unsigned int* p, unsigned int want) {
  if (want)
    while (__hip_atomic_load(p, __ATOMIC_RELAXED, __HIP_MEMORY_SCOPE_AGENT) < want)
      __builtin_amdgcn_s_sleep(1);
}

__device__ __forceinline__ float sigmoid_f(float x) { return 1.f / (1.f + __expf(-x)); }
__device__ __forceinline__ float tanh_f(float x)    { return 1.f - 2.f / (__expf(2.f*x) + 1.f); }

// ---------------------------------------------------------------------------
// Persistent wavefront-pipelined GRU.
// 192 WGs = 3 layers x 4 batch-quarters x 16 col-slices. 384 thr = 6 waves:
//   waves 0-2: rec gates r/z/n (Whh slice in VGPRs), step t
//   waves 3-5: xp gates r/z/n (Wih slice in VGPRs), step t+1 (one ahead)
// h broadcast through IC: LDS-staged dwordx4 write-through stores (sc0 sc1),
// one aggregated atomicAdd counter per (layer,bq); 2 polling lanes per WG.
// ---------------------------------------------------------------------------
__global__ __launch_bounds__(384, 2)
void gru_persist(const unsigned short* __restrict__ xbf,
                 unsigned short* __restrict__ seq0,
                 unsigned short* __restrict__ seq1,
                 unsigned short* __restrict__ seq2,
                 unsigned int* __restrict__ flags,
                 const float* __restrict__ Wih0, const float* __restrict__ Whh0,
                 const float* __restrict__ bih0, const float* __restrict__ bhh0,
                 const float* __restrict__ Wih1, const float* __restrict__ Whh1,
                 const float* __restrict__ bih1, const float* __restrict__ bhh1,
                 const float* __restrict__ Wih2, const float* __restrict__ Whh2,
                 const float* __restrict__ bih2, const float* __restrict__ bhh2)
{
  __shared__ float xpL[2][3][16][33];        // [slot][gate][row][col] xp (incl bih)
  __shared__ float rzL[2][16][33];           // [r/z][row][col] sigmoids
  __shared__ unsigned short htile[16*32];    // h(t) staging for coalesced store

  const int tid  = threadIdx.x;
  const int wid  = tid >> 6;
  const int lane = tid & 63;
  const int col  = lane & 15;     // n / m index
  const int quad = lane >> 4;     // k-group / row-quad

  const int wg = blockIdx.x;
  const int l  = wg >> 6;          // layer 0..2
  const int rr = wg & 63;
  const int bq = rr >> 4;          // batch quarter
  const int cq = rr & 15;          // col slice
  const int c0 = cq * 32;
  const int b0 = bq * 16;

  unsigned short* seqw = (l==0) ? seq0 : (l==1) ? seq1 : seq2;
  const unsigned short* seqr = (l==1) ? seq0 : (l==2) ? seq1 : (const unsigned short*)0;

  const bool isrec = (wid < 3);
  const int  g     = isrec ? wid : wid - 3;

  const float* Whh = (l==0)?Whh0:(l==1)?Whh1:Whh2;
  const float* Wih = (l==0)?Wih0:(l==1)?Wih1:Wih2;
  const float* bhh = (l==0)?bhh0:(l==1)?bhh1:bhh2;
  const float* bih = (l==0)?bih0:(l==1)?bih1:bih2;

  const float* Wsrc = isrec ? Whh : Wih;
  const int K  = isrec ? NH : ((l==0) ? NF : NH);
  const int KT = K >> 5;                 // 32-wide k-tiles: 16 or 4

  // ---- preload weight slice into VGPRs (B-frag order), bf16 ----
  s16x8 wr0[16], wr1[16];
  #pragma unroll
  for (int kt = 0; kt < 16; ++kt) {
    if (kt < KT) {
      const float* s0 = Wsrc + (size_t)(g*NH + c0 +      col) * K + kt*32 + quad*8;
      const float* s1 = Wsrc + (size_t)(g*NH + c0 + 16 + col) * K + kt*32 + quad*8;
      s16x8 w0, w1;
      #pragma unroll
      for (int j = 0; j < 8; ++j) { w0[j] = (short)f2bf(s0[j]); w1[j] = (short)f2bf(s1[j]); }
      wr0[kt] = w0; wr1[kt] = w1;
    } else { wr0[kt] = (s16x8)0; wr1[kt] = (s16x8)0; }
  }
  const float* bb = isrec ? bhh : bih;
  const float bias0 = bb[g*NH + c0 +      col];
  const float bias1 = bb[g*NH + c0 + 16 + col];

  unsigned int* cnt_self = flags + (size_t)(l*4 + bq)*16;        // 64B apart
  unsigned int* cnt_prev = (l > 0) ? (flags + (size_t)((l-1)*4 + bq)*16) : cnt_self;

  // ---- prologue: wait prev layer t<=1 done, then xp(0) into slot 0 ----
  if (l > 0 && tid == 0) waitge(cnt_prev, 32u);
  __syncthreads();
  if (!isrec) {
    f32x4 a0 = {0.f,0.f,0.f,0.f}, a1 = {0.f,0.f,0.f,0.f};
    const unsigned short* ar = (l==0)
        ? xbf  + (size_t)(b0+col)*NT*NF + quad*8
        : seqr + (size_t)(b0+col)*NT*NH + quad*8;
    #pragma unroll
    for (int kt = 0; kt < 16; ++kt) if (kt < KT) {
      s16x8 a = *(const s16x8*)(ar + kt*32);
      a0 = __builtin_amdgcn_mfma_f32_16x16x32_bf16(a, wr0[kt], a0, 0, 0, 0);
      a1 = __builtin_amdgcn_mfma_f32_16x16x32_bf16(a, wr1[kt], a1, 0, 0, 0);
    }
    #pragma unroll
    for (int i = 0; i < 4; ++i) {
      int row = quad*4 + i;
      xpL[0][g][row][col]      = a0[i] + bias0;
      xpL[0][g][row][col + 16] = a1[i] + bias1;
    }
  }
  __syncthreads();

  float hp0[4] = {0.f,0.f,0.f,0.f}, hp1[4] = {0.f,0.f,0.f,0.f};  // n-wave h state

  for (int t = 0; t < NT; ++t) {
    const int slot  = t & 1;
    const int nslot = slot ^ 1;

    f32x4 a0 = {0.f,0.f,0.f,0.f}, a1 = {0.f,0.f,0.f,0.f};

    // ---------------- phase 1: MFMA ----------------
    if (isrec) {
      if (t > 0) {
        const unsigned short* ar = seqw + ((size_t)(b0+col)*NT + (t-1))*NH + quad*8;
        #pragma unroll
        for (int kt = 0; kt < 16; ++kt) {
          s16x8 a = *(const s16x8*)(ar + kt*32);
          a0 = __builtin_amdgcn_mfma_f32_16x16x32_bf16(a, wr0[kt], a0, 0, 0, 0);
          a1 = __builtin_amdgcn_mfma_f32_16x16x32_bf16(a, wr1[kt], a1, 0, 0, 0);
        }
      }
      if (g < 2) {       // r/z: sigmoid -> LDS
        #pragma unroll
        for (int i = 0; i < 4; ++i) {
          int row = quad*4 + i;
          float p0 = a0[i] + xpL[slot][g][row][col]      + bias0;
          float p1 = a1[i] + xpL[slot][g][row][col + 16] + bias1;
          rzL[g][row][col]      = sigmoid_f(p0);
          rzL[g][row][col + 16] = sigmoid_f(p1);
        }
      } else {           // n: keep pre-activation hn (+bhh_n) in regs
        #pragma unroll
        for (int i = 0; i < 4; ++i) { a0[i] += bias0; a1[i] += bias1; }
      }
    } else {             // xp waves: compute xp(t+1); visibility ensured by poll at t-1
      if (t + 1 < NT) {
        const unsigned short* ar = (l==0)
            ? xbf  + ((size_t)(b0+col)*NT + (t+1))*NF + quad*8
            : seqr + ((size_t)(b0+col)*NT + (t+1))*NH + quad*8;
        #pragma unroll
        for (int kt = 0; kt < 16; ++kt) if (kt < KT) {
          s16x8 a = *(const s16x8*)(ar + kt*32);
          a0 = __builtin_amdgcn_mfma_f32_16x16x32_bf16(a, wr0[kt], a0, 0, 0, 0);
          a1 = __builtin_amdgcn_mfma_f32_16x16x32_bf16(a, wr1[kt], a1, 0, 0, 0);
        }
      }
    }
    __syncthreads();   // B1: rz + xp accs ready

    // ---------------- phase 2: update + store + sync ----------------
    if (wid == 0) {
      // idle r-wave overlaps the polls for iteration t+1 with wave 2's store
      if (lane < 2) {
        unsigned int* pp = (lane == 0) ? cnt_self : cnt_prev;
        unsigned int tg = 0;
        if (lane == 0) { if (t + 1 < NT) tg = 16u*(unsigned)(t + 1); }
        else           { if (l > 0 && t + 2 < NT) tg = 16u*(unsigned)(t + 3); }
        waitge(pp, tg);
      }
    } else if (wid == 2) {      // n-wave: gate combine, h update, coalesced IC store
      #pragma unroll
      for (int i = 0; i < 4; ++i) {
        int row = quad*4 + i;
        float xn0 = xpL[slot][2][row][col];
        float xn1 = xpL[slot][2][row][col + 16];
        float rt0 = rzL[0][row][col],      rt1 = rzL[0][row][col + 16];
        float zt0 = rzL[1][row][col],      zt1 = rzL[1][row][col + 16];
        float nv0 = tanh_f(xn0 + rt0 * a0[i]);
        float nv1 = tanh_f(xn1 + rt1 * a1[i]);
        float h0 = (1.f - zt0)*nv0 + zt0*hp0[i];
        float h1 = (1.f - zt1)*nv1 + zt1*hp1[i];
        hp0[i] = h0; hp1[i] = h1;
        htile[row*32 + col]      = f2bf(h0);
        htile[row*32 + col + 16] = f2bf(h1);
      }
      // coalesced write-through: 1 dwordx4 per lane covers the 1KB tile
      {
        int srow = lane >> 2, sch = lane & 3;
        s16x8 hv = *(const s16x8*)&htile[srow*32 + sch*8];
        unsigned short* p = seqw + ((size_t)(b0+srow)*NT + t)*NH + c0 + sch*8;
        asm volatile("global_store_dwordx4 %0, %1, off sc0 sc1" :: "v"(p), "v"(hv) : "memory");
        asm volatile("s_waitcnt vmcnt(0)" ::: "memory");   // h visible at IC
      }
      if (lane == 0)
        __hip_atomic_fetch_add(cnt_self, 1u, __ATOMIC_RELAXED, __HIP_MEMORY_SCOPE_AGENT);
    } else if (!isrec && t + 1 < NT) {   // xp: regs -> LDS slot t+1
      #pragma unroll
      for (int i = 0; i < 4; ++i) {
        int row = quad*4 + i;
        xpL[nslot][g][row][col]      = a0[i] + bias0;
        xpL[nslot][g][row][col + 16] = a1[i] + bias1;
      }
    }
    __syncthreads();   // B2: polls satisfied, xp slot ready -> next iter
  }
}

// ---------------- head GEMM: out[bt][o] = seq2[bt][:] . Wout[o][:] + bout ----
__global__ __launch_bounds__(256)
void head_gemm(const unsigned short* __restrict__ seq2,
               const unsigned short* __restrict__ woutb,
               const float* __restrict__ bout,
               float* __restrict__ out)
{
  int tid = threadIdx.x;
  int wv = tid >> 6, lane = tid & 63;
  int col = lane & 31, khi = lane >> 5;
  int id = blockIdx.x*4 + wv;
  int mt = id >> 2, nt = id & 3;
  int m0 = mt*32, n0 = nt*32;
  const unsigned short* arow = seq2  + (size_t)(m0 + col)*NH + (khi << 3);
  const unsigned short* brow = woutb + (size_t)(n0 + col)*NH + (khi << 3);
  f32x16 acc;
  #pragma unroll
  for (int i = 0; i < 16; ++i) acc[i] = 0.f;
  #pragma unroll 8
  for (int kt = 0; kt < 32; ++kt) {
    s16x8 a = *(const s16x8*)(arow + kt*16);
    s16x8 b = *(const s16x8*)(brow + kt*16);
    acc = __builtin_amdgcn_mfma_f32_32x32x16_bf16(a, b, acc, 0, 0, 0);
  }
  float bo = bout[n0 + col];
  #pragma unroll
  for (int r = 0; r < 16; ++r) {
    int row = (r & 3) + ((r >> 2) << 3) + (khi << 2);
    out[(size_t)(m0 + row)*NO + n0 + col] = acc[r] + bo;
  }
}

__global__ void cast_f32_bf16(const float* __restrict__ src,
                              unsigned short* __restrict__ dst, int n) {
  int i = blockIdx.x*blockDim.x + threadIdx.x;
  int stride = gridDim.x*blockDim.x;
  for (; i < n; i += stride) dst[i] = f2bf(src[i]);
}

extern "C" void kernel_launch(void* const* d_in, const int* in_sizes, int n_in,
                              void* d_out, int out_size, void* d_ws, size_t ws_size,
                              hipStream_t stream) {
  (void)in_sizes; (void)n_in; (void)out_size; (void)ws_size;
  const float* x    = (const float*)d_in[0];
  const float* Wih0 = (const float*)d_in[1];
  const float* Whh0 = (const float*)d_in[2];
  const float* bih0 = (const float*)d_in[3];
  const float* bhh0 = (const float*)d_in[4];
  const float* Wih1 = (const float*)d_in[5];
  const float* Whh1 = (const float*)d_in[6];
  const float* bih1 = (const float*)d_in[7];
  const float* bhh1 = (const float*)d_in[8];
  const float* Wih2 = (const float*)d_in[9];
  const float* Whh2 = (const float*)d_in[10];
  const float* bih2 = (const float*)d_in[11];
  const float* bhh2 = (const float*)d_in[12];
  const float* Wout = (const float*)d_in[13];
  const float* bout = (const float*)d_in[14];

  char* ws = (char*)d_ws;
  unsigned short* xbf  = (unsigned short*)(ws + OFF_XBF);
  unsigned short* wob  = (unsigned short*)(ws + OFF_WOUT);
  unsigned short* seq0 = (unsigned short*)(ws + OFF_SEQ0);
  unsigned short* seq1 = (unsigned short*)(ws + OFF_SEQ1);
  unsigned short* seq2 = (unsigned short*)(ws + OFF_SEQ2);
  unsigned int*   flg  = (unsigned int*)(ws + OFF_FLAGS);

  hipMemsetAsync(ws + OFF_FLAGS, 0, 4096, stream);
  cast_f32_bf16<<<512, 256, 0, stream>>>(x, xbf, NB*NT*NF);
  cast_f32_bf16<<<64, 256, 0, stream>>>(Wout, wob, NO*NH);
  gru_persist<<<192, 384, 0, stream>>>(xbf, seq0, seq1, seq2, flg,
      Wih0, Whh0, bih0, bhh0, Wih1, Whh1, bih1, bhh1, Wih2, Whh2, bih2, bhh2);
  head_gemm<<<1024, 256, 0, stream>>>(seq2, wob, bout, (float*)d_out);
}

// Round 4
// 3532.576 us; speedup vs baseline: 1.0818x; 1.0818x over previous
//
#include <hip/hip_runtime.h>
#include <stdint.h>
#include <math.h>

#define NB 64
#define NT 512
#define NF 128
#define NH 512
#define NO 128

typedef short  s16x8  __attribute__((ext_vector_type(8)));   // 8 bf16
typedef float  f32x4  __attribute__((ext_vector_type(4)));   // 16x16 acc
typedef float  f32x16 __attribute__((ext_vector_type(16)));  // 32x32 acc (head)

// ---------------- workspace layout (bytes) ----------------
#define OFF_XBF   ((size_t)0)                      // B*T*F bf16 = 8 MB
#define OFF_WOUT  ((size_t)(8u<<20))               // O*H bf16 = 128 KB
#define OFF_SEQ0  ((size_t)(12u<<20))              // B*T*H bf16 = 32 MB
#define OFF_SEQ1  (OFF_SEQ0 + ((size_t)32u<<20))
#define OFF_SEQ2  (OFF_SEQ1 + ((size_t)32u<<20))
#define OFF_FLAGS (OFF_SEQ2 + ((size_t)32u<<20))   // 12 lines x 16 dwords

#define SMEM_BYTES 88064   // > 80 KB -> exactly 1 WG per CU (160 KB LDS pool)

__device__ __forceinline__ unsigned short f2bf(float f) {
  unsigned int u = __float_as_uint(f);
  u += 0x7fffu + ((u >> 16) & 1u);   // RNE
  return (unsigned short)(u >> 16);
}

__device__ __forceinline__ unsigned int ld_flag(unsigned int* p) {
  return __hip_atomic_load(p, __ATOMIC_RELAXED, __HIP_MEMORY_SCOPE_AGENT);
}

// poll 4 consecutive flag slots until min >= tgt (call from lanes 0..3)
__device__ __forceinline__ void poll4(unsigned int* line, int j, unsigned int tgt) {
  unsigned int* p = line + j*4;
  for (;;) {
    unsigned int a = ld_flag(p+0), b = ld_flag(p+1);
    unsigned int c = ld_flag(p+2), d = ld_flag(p+3);
    unsigned int m = min(min(a,b), min(c,d));
    if (m >= tgt) break;
    __builtin_amdgcn_s_sleep(1);
  }
}

__device__ __forceinline__ float sigmoid_f(float x) { return 1.f / (1.f + __expf(-x)); }
__device__ __forceinline__ float tanh_f(float x)    { return 1.f - 2.f / (__expf(2.f*x) + 1.f); }

// ---------------------------------------------------------------------------
// Persistent wavefront-pipelined GRU.
// 192 WGs (1 per CU, forced by 88KB LDS) = 3 layers x 4 bq x 16 col-slices.
// 6 waves: 0-2 rec gates r/z/n (step t), 3-5 xp gates (step t+1).
// Phase 1: rec poll+load+MFMA (+ wave3 polls prev layer).
// Phase 2: n-wave epilogue/store/flag  ||  xp waves load+MFMA -> xpL[nslot].
// Flags: per-producer dword slots (no atomics), sc0/sc1 write-through h.
// ---------------------------------------------------------------------------
__global__ __launch_bounds__(384, 1)
void gru_persist(const unsigned short* __restrict__ xbf,
                 unsigned short* __restrict__ seq0,
                 unsigned short* __restrict__ seq1,
                 unsigned short* __restrict__ seq2,
                 unsigned int* __restrict__ flags,
                 const float* __restrict__ Wih0, const float* __restrict__ Whh0,
                 const float* __restrict__ bih0, const float* __restrict__ bhh0,
                 const float* __restrict__ Wih1, const float* __restrict__ Whh1,
                 const float* __restrict__ bih1, const float* __restrict__ bhh1,
                 const float* __restrict__ Wih2, const float* __restrict__ Whh2,
                 const float* __restrict__ bih2, const float* __restrict__ bhh2)
{
  extern __shared__ char smem[];
  float (*xpL)[3][16][33] = (float (*)[3][16][33])smem;          // 2 slots, 12672 B
  float (*rzL)[16][33]    = (float (*)[16][33])(smem + 12672);   // 2 gates, 4224 B
  unsigned short* htile   = (unsigned short*)(smem + 12672 + 4224); // 1024 B

  const int tid  = threadIdx.x;
  const int wid  = tid >> 6;
  const int lane = tid & 63;
  const int col  = lane & 15;     // n / m index
  const int quad = lane >> 4;     // k-group / row-quad

  const int wg = blockIdx.x;
  const int l  = wg >> 6;          // layer 0..2
  const int rr = wg & 63;
  const int bq = rr >> 4;          // batch quarter
  const int cq = rr & 15;          // col slice
  const int c0 = cq * 32;
  const int b0 = bq * 16;

  unsigned short* seqw = (l==0) ? seq0 : (l==1) ? seq1 : seq2;
  const unsigned short* seqr = (l==1) ? seq0 : (l==2) ? seq1 : (const unsigned short*)0;

  const bool isrec = (wid < 3);
  const int  g     = isrec ? wid : wid - 3;

  const float* Whh = (l==0)?Whh0:(l==1)?Whh1:Whh2;
  const float* Wih = (l==0)?Wih0:(l==1)?Wih1:Wih2;
  const float* bhh = (l==0)?bhh0:(l==1)?bhh1:bhh2;
  const float* bih = (l==0)?bih0:(l==1)?bih1:bih2;

  const float* Wsrc = isrec ? Whh : Wih;
  const int K  = isrec ? NH : ((l==0) ? NF : NH);
  const int KT = K >> 5;                 // 32-wide k-tiles: 16 or 4

  // ---- preload weight slice into regs (B-frag order), bf16 ----
  s16x8 wr0[16], wr1[16];
  #pragma unroll
  for (int kt = 0; kt < 16; ++kt) {
    if (kt < KT) {
      const float* s0 = Wsrc + (size_t)(g*NH + c0 +      col) * K + kt*32 + quad*8;
      const float* s1 = Wsrc + (size_t)(g*NH + c0 + 16 + col) * K + kt*32 + quad*8;
      s16x8 w0, w1;
      #pragma unroll
      for (int j = 0; j < 8; ++j) { w0[j] = (short)f2bf(s0[j]); w1[j] = (short)f2bf(s1[j]); }
      wr0[kt] = w0; wr1[kt] = w1;
    } else { wr0[kt] = (s16x8)0; wr1[kt] = (s16x8)0; }
  }
  const float* bb = isrec ? bhh : bih;
  const float bias0 = bb[g*NH + c0 +      col];
  const float bias1 = bb[g*NH + c0 + 16 + col];

  unsigned int* line_self = flags + (size_t)(l*4 + bq)*16;
  unsigned int* line_prev = (l > 0) ? (flags + (size_t)((l-1)*4 + bq)*16) : line_self;

  // ---- prologue: xp(0) into slot 0 ----
  if (!isrec) {
    if (l > 0 && lane < 4) poll4(line_prev, lane, 1u);   // seqr(:,0) ready
    asm volatile("" ::: "memory");
    f32x4 a0 = {0.f,0.f,0.f,0.f}, a1 = {0.f,0.f,0.f,0.f};
    const unsigned short* ar = (l==0)
        ? xbf  + (size_t)(b0+col)*NT*NF + quad*8
        : seqr + (size_t)(b0+col)*NT*NH + quad*8;
    #pragma unroll
    for (int kt = 0; kt < 16; ++kt) if (kt < KT) {
      s16x8 a = *(const s16x8*)(ar + kt*32);
      a0 = __builtin_amdgcn_mfma_f32_16x16x32_bf16(a, wr0[kt], a0, 0, 0, 0);
      a1 = __builtin_amdgcn_mfma_f32_16x16x32_bf16(a, wr1[kt], a1, 0, 0, 0);
    }
    #pragma unroll
    for (int i = 0; i < 4; ++i) {
      int row = quad*4 + i;
      xpL[0][g][row][col]      = a0[i] + bias0;
      xpL[0][g][row][col + 16] = a1[i] + bias1;
    }
  }
  __syncthreads();

  float hp0[4] = {0.f,0.f,0.f,0.f}, hp1[4] = {0.f,0.f,0.f,0.f};  // n-wave h state

  for (int t = 0; t < NT; ++t) {
    const int slot  = t & 1;
    const int nslot = slot ^ 1;

    f32x4 a0 = {0.f,0.f,0.f,0.f}, a1 = {0.f,0.f,0.f,0.f};

    // ---------------- phase 1: rec MFMA + polls ----------------
    if (isrec) {
      if (t > 0) {
        if (lane < 4) poll4(line_self, lane, (unsigned)t);   // h(t-1) from all peers
        asm volatile("" ::: "memory");
        const unsigned short* ar = seqw + ((size_t)(b0+col)*NT + (t-1))*NH + quad*8;
        #pragma unroll
        for (int kt = 0; kt < 16; ++kt) {
          s16x8 a = *(const s16x8*)(ar + kt*32);
          a0 = __builtin_amdgcn_mfma_f32_16x16x32_bf16(a, wr0[kt], a0, 0, 0, 0);
          a1 = __builtin_amdgcn_mfma_f32_16x16x32_bf16(a, wr1[kt], a1, 0, 0, 0);
        }
      }
      if (g < 2) {       // r/z: sigmoid -> LDS
        #pragma unroll
        for (int i = 0; i < 4; ++i) {
          int row = quad*4 + i;
          float p0 = a0[i] + xpL[slot][g][row][col]      + bias0;
          float p1 = a1[i] + xpL[slot][g][row][col + 16] + bias1;
          rzL[g][row][col]      = sigmoid_f(p0);
          rzL[g][row][col + 16] = sigmoid_f(p1);
        }
      } else {           // n: keep pre-activation hn (+bhh_n) in regs
        #pragma unroll
        for (int i = 0; i < 4; ++i) { a0[i] += bias0; a1[i] += bias1; }
      }
    } else if (wid == 3) {
      // poll for phase-2's xp(t+1) read of seqr(:,t+1); B1 propagates to waves 4,5
      if (l > 0 && t + 1 < NT && lane < 4) poll4(line_prev, lane, (unsigned)(t + 2));
    }
    __syncthreads();   // B1

    // ---------------- phase 2: n-epilogue/store  ||  xp(t+1) ----------------
    if (wid == 2) {      // n-wave: gate combine, h update, coalesced IC store, flag
      #pragma unroll
      for (int i = 0; i < 4; ++i) {
        int row = quad*4 + i;
        float xn0 = xpL[slot][2][row][col];
        float xn1 = xpL[slot][2][row][col + 16];
        float rt0 = rzL[0][row][col],      rt1 = rzL[0][row][col + 16];
        float zt0 = rzL[1][row][col],      zt1 = rzL[1][row][col + 16];
        float nv0 = tanh_f(xn0 + rt0 * a0[i]);
        float nv1 = tanh_f(xn1 + rt1 * a1[i]);
        float h0 = (1.f - zt0)*nv0 + zt0*hp0[i];
        float h1 = (1.f - zt1)*nv1 + zt1*hp1[i];
        hp0[i] = h0; hp1[i] = h1;
        htile[row*32 + col]      = f2bf(h0);
        htile[row*32 + col + 16] = f2bf(h1);
      }
      __builtin_amdgcn_s_waitcnt(0);  // lgkm: htile visible wave-wide
      {
        int srow = lane >> 2, sch = lane & 3;
        s16x8 hv = *(const s16x8*)&htile[srow*32 + sch*8];
        unsigned short* p = seqw + ((size_t)(b0+srow)*NT + t)*NH + c0 + sch*8;
        asm volatile("global_store_dwordx4 %0, %1, off sc0 sc1" :: "v"(p), "v"(hv) : "memory");
        asm volatile("s_waitcnt vmcnt(0)" ::: "memory");   // h at coherence point
      }
      if (lane == 0)
        __hip_atomic_store(line_self + cq, (unsigned)(t + 1),
                           __ATOMIC_RELAXED, __HIP_MEMORY_SCOPE_AGENT);
    } else if (!isrec && t + 1 < NT) {   // xp waves: compute xp(t+1) -> xpL[nslot]
      const unsigned short* ar = (l==0)
          ? xbf  + ((size_t)(b0+col)*NT + (t+1))*NF + quad*8
          : seqr + ((size_t)(b0+col)*NT + (t+1))*NH + quad*8;
      #pragma unroll
      for (int kt = 0; kt < 16; ++kt) if (kt < KT) {
        s16x8 a = *(const s16x8*)(ar + kt*32);
        a0 = __builtin_amdgcn_mfma_f32_16x16x32_bf16(a, wr0[kt], a0, 0, 0, 0);
        a1 = __builtin_amdgcn_mfma_f32_16x16x32_bf16(a, wr1[kt], a1, 0, 0, 0);
      }
      #pragma unroll
      for (int i = 0; i < 4; ++i) {
        int row = quad*4 + i;
        xpL[nslot][g][row][col]      = a0[i] + bias0;
        xpL[nslot][g][row][col + 16] = a1[i] + bias1;
      }
    }
    __syncthreads();   // B2
  }
}

// ---------------- head GEMM: out[bt][o] = seq2[bt][:] . Wout[o][:] + bout ----
__global__ __launch_bounds__(256)
void head_gemm(const unsigned short* __restrict__ seq2,
               const unsigned short* __restrict__ woutb,
               const float* __restrict__ bout,
               float* __restrict__ out)
{
  int tid = threadIdx.x;
  int wv = tid >> 6, lane = tid & 63;
  int col = lane & 31, khi = lane >> 5;
  int id = blockIdx.x*4 + wv;
  int mt = id >> 2, nt = id & 3;
  int m0 = mt*32, n0 = nt*32;
  const unsigned short* arow = seq2  + (size_t)(m0 + col)*NH + (khi << 3);
  const unsigned short* brow = woutb + (size_t)(n0 + col)*NH + (khi << 3);
  f32x16 acc;
  #pragma unroll
  for (int i = 0; i < 16; ++i) acc[i] = 0.f;
  #pragma unroll 8
  for (int kt = 0; kt < 32; ++kt) {
    s16x8 a = *(const s16x8*)(arow + kt*16);
    s16x8 b = *(const s16x8*)(brow + kt*16);
    acc = __builtin_amdgcn_mfma_f32_32x32x16_bf16(a, b, acc, 0, 0, 0);
  }
  float bo = bout[n0 + col];
  #pragma unroll
  for (int r = 0; r < 16; ++r) {
    int row = (r & 3) + ((r >> 2) << 3) + (khi << 2);
    out[(size_t)(m0 + row)*NO + n0 + col] = acc[r] + bo;
  }
}

__global__ void cast_f32_bf16(const float* __restrict__ src,
                              unsigned short* __restrict__ dst, int n) {
  int i = blockIdx.x*blockDim.x + threadIdx.x;
  int stride = gridDim.x*blockDim.x;
  for (; i < n; i += stride) dst[i] = f2bf(src[i]);
}

extern "C" void kernel_launch(void* const* d_in, const int* in_sizes, int n_in,
                              void* d_out, int out_size, void* d_ws, size_t ws_size,
                              hipStream_t stream) {
  (void)in_sizes; (void)n_in; (void)out_size; (void)ws_size;
  const float* x    = (const float*)d_in[0];
  const float* Wih0 = (const float*)d_in[1];
  const float* Whh0 = (const float*)d_in[2];
  const float* bih0 = (const float*)d_in[3];
  const float* bhh0 = (const float*)d_in[4];
  const float* Wih1 = (const float*)d_in[5];
  const float* Whh1 = (const float*)d_in[6];
  const float* bih1 = (const float*)d_in[7];
  const float* bhh1 = (const float*)d_in[8];
  const float* Wih2 = (const float*)d_in[9];
  const float* Whh2 = (const float*)d_in[10];
  const float* bih2 = (const float*)d_in[11];
  const float* bhh2 = (const float*)d_in[12];
  const float* Wout = (const float*)d_in[13];
  const float* bout = (const float*)d_in[14];

  char* ws = (char*)d_ws;
  unsigned short* xbf  = (unsigned short*)(ws + OFF_XBF);
  unsigned short* wob  = (unsigned short*)(ws + OFF_WOUT);
  unsigned short* seq0 = (unsigned short*)(ws + OFF_SEQ0);
  unsigned short* seq1 = (unsigned short*)(ws + OFF_SEQ1);
  unsigned short* seq2 = (unsigned short*)(ws + OFF_SEQ2);
  unsigned int*   flg  = (unsigned int*)(ws + OFF_FLAGS);

  // allow >64KB dynamic LDS (idempotent, capture-safe)
  (void)hipFuncSetAttribute((const void*)gru_persist,
                            hipFuncAttributeMaxDynamicSharedMemorySize, 160*1024);

  hipMemsetAsync(ws + OFF_FLAGS, 0, 4096, stream);
  cast_f32_bf16<<<512, 256, 0, stream>>>(x, xbf, NB*NT*NF);
  cast_f32_bf16<<<64, 256, 0, stream>>>(Wout, wob, NO*NH);
  gru_persist<<<192, 384, SMEM_BYTES, stream>>>(xbf, seq0, seq1, seq2, flg,
      Wih0, Whh0, bih0, bhh0, Wih1, Whh1, bih1, bhh1, Wih2, Whh2, bih2, bhh2);
  head_gemm<<<1024, 256, 0, stream>>>(seq2, wob, bout, (float*)d_out);
}

// Round 5
// 2942.085 us; speedup vs baseline: 1.2989x; 1.2007x over previous
//
#include <hip/hip_runtime.h>
#include <stdint.h>
#include <math.h>

#define NB 64
#define NT 512
#define NF 128
#define NH 512
#define NO 128
#define HSTR 520   // LDS A-tile row stride in shorts (512 + 8 pad)

typedef short  s16x8  __attribute__((ext_vector_type(8)));   // 8 bf16
typedef float  f32x4  __attribute__((ext_vector_type(4)));   // 16x16 acc
typedef float  f32x16 __attribute__((ext_vector_type(16)));  // 32x32 acc (head)

// ---------------- workspace layout (bytes) ----------------
#define OFF_XBF   ((size_t)0)                      // B*T*F bf16 = 8 MB
#define OFF_WOUT  ((size_t)(8u<<20))               // O*H bf16 = 128 KB
#define OFF_SEQ0  ((size_t)(12u<<20))              // B*T*H bf16 = 32 MB
#define OFF_SEQ1  (OFF_SEQ0 + ((size_t)32u<<20))
#define OFF_SEQ2  (OFF_SEQ1 + ((size_t)32u<<20))
#define OFF_FLAGS (OFF_SEQ2 + ((size_t)32u<<20))   // 12 lines x 16 dwords

#define SMEM_BYTES 88064   // > 80 KB -> exactly 1 WG per CU (160 KB LDS pool)

__device__ __forceinline__ unsigned short f2bf(float f) {
  unsigned int u = __float_as_uint(f);
  u += 0x7fffu + ((u >> 16) & 1u);   // RNE
  return (unsigned short)(u >> 16);
}

__device__ __forceinline__ unsigned int ld_flag(unsigned int* p) {
  return __hip_atomic_load(p, __ATOMIC_RELAXED, __HIP_MEMORY_SCOPE_AGENT);
}

// poll 4 consecutive flag slots until min >= tgt (call from lanes 0..3)
__device__ __forceinline__ void poll4(unsigned int* line, int j, unsigned int tgt) {
  unsigned int* p = line + j*4;
  for (;;) {
    unsigned int a = ld_flag(p+0), b = ld_flag(p+1);
    unsigned int c = ld_flag(p+2), d = ld_flag(p+3);
    unsigned int m = min(min(a,b), min(c,d));
    if (m >= tgt) break;
    __builtin_amdgcn_s_sleep(1);
  }
}

__device__ __forceinline__ float sigmoid_f(float x) { return 1.f / (1.f + __expf(-x)); }
__device__ __forceinline__ float tanh_f(float x)    { return 1.f - 2.f / (__expf(2.f*x) + 1.f); }

// ---------------------------------------------------------------------------
// Persistent wavefront-pipelined GRU, transport software-pipelined into phase 2.
// 192 WGs (1/CU) = 3 layers x 4 bq x 16 col-slices. 6 waves:
//   waves 0-2: rec gates r/z/n (step t) — phase 1 = LDS->MFMA only
//   waves 3-5: xp gates (step t+1)     — phase 1 = LDS->MFMA only
// Phase 2: wave2 = n-epilogue + sc1 h-store + flag
//          waves 0,1 = poll peers + stage hA( h(t) )      [plain loads]
//          waves 3,4 = poll prev  + stage xA( src(t+2) )  [plain loads]
// ---------------------------------------------------------------------------
__global__ __launch_bounds__(384, 1)
void gru_persist(const unsigned short* __restrict__ xbf,
                 unsigned short* __restrict__ seq0,
                 unsigned short* __restrict__ seq1,
                 unsigned short* __restrict__ seq2,
                 unsigned int* __restrict__ flags,
                 const float* __restrict__ Wih0, const float* __restrict__ Whh0,
                 const float* __restrict__ bih0, const float* __restrict__ bhh0,
                 const float* __restrict__ Wih1, const float* __restrict__ Whh1,
                 const float* __restrict__ bih1, const float* __restrict__ bhh1,
                 const float* __restrict__ Wih2, const float* __restrict__ Whh2,
                 const float* __restrict__ bih2, const float* __restrict__ bhh2)
{
  extern __shared__ char smem[];
  unsigned short* hA = (unsigned short*)smem;                  // 16 x 520 shorts
  unsigned short* xA = (unsigned short*)(smem + 16640);        // 16 x 520 shorts
  float (*xpL)[3][16][33] = (float (*)[3][16][33])(smem + 33280); // 2 slots
  float (*rzL)[16][33]    = (float (*)[16][33])(smem + 45952);    // r/z
  unsigned short* hout    = (unsigned short*)(smem + 50176);      // 1 KB

  const int tid  = threadIdx.x;
  const int wid  = tid >> 6;
  const int lane = tid & 63;
  const int col  = lane & 15;     // n / m index
  const int quad = lane >> 4;     // k-group / row-quad

  const int wg = blockIdx.x;
  const int l  = wg >> 6;          // layer 0..2
  const int rr = wg & 63;
  const int bq = rr >> 4;          // batch quarter
  const int cq = rr & 15;          // col slice
  const int c0 = cq * 32;
  const int b0 = bq * 16;

  unsigned short* seqw = (l==0) ? seq0 : (l==1) ? seq1 : seq2;
  const unsigned short* seqr = (l==1) ? seq0 : (l==2) ? seq1 : (const unsigned short*)0;

  const bool isrec = (wid < 3);
  const int  g     = isrec ? wid : wid - 3;

  const float* Whh = (l==0)?Whh0:(l==1)?Whh1:Whh2;
  const float* Wih = (l==0)?Wih0:(l==1)?Wih1:Wih2;
  const float* bhh = (l==0)?bhh0:(l==1)?bhh1:bhh2;
  const float* bih = (l==0)?bih0:(l==1)?bih1:bih2;

  const float* Wsrc = isrec ? Whh : Wih;
  const int K   = isrec ? NH : ((l==0) ? NF : NH);
  const int KT  = K >> 5;                 // 16 (K=512) or 4 (K=128)
  const int KTx = (l==0) ? 4 : 16;        // xp tile count
  const int xrow = (l==0) ? NF : NH;      // xp source row length (shorts)

  // ---- preload weight slice into regs (B-frag order), bf16 ----
  s16x8 wr0[16], wr1[16];
  #pragma unroll
  for (int kt = 0; kt < 16; ++kt) {
    if (kt < KT) {
      const float* s0 = Wsrc + (size_t)(g*NH + c0 +      col) * K + kt*32 + quad*8;
      const float* s1 = Wsrc + (size_t)(g*NH + c0 + 16 + col) * K + kt*32 + quad*8;
      s16x8 w0, w1;
      #pragma unroll
      for (int j = 0; j < 8; ++j) { w0[j] = (short)f2bf(s0[j]); w1[j] = (short)f2bf(s1[j]); }
      wr0[kt] = w0; wr1[kt] = w1;
    } else { wr0[kt] = (s16x8)0; wr1[kt] = (s16x8)0; }
  }
  const float* bb = isrec ? bhh : bih;
  const float bias0 = bb[g*NH + c0 +      col];
  const float bias1 = bb[g*NH + c0 + 16 + col];

  unsigned int* line_self = flags + (size_t)(l*4 + bq)*16;
  unsigned int* line_prev = (l > 0) ? (flags + (size_t)((l-1)*4 + bq)*16) : line_self;

  // stage a 16-row A-tile (rows b0..b0+15, time `step`) into LDS.
  // Called by a wave pair (half = 0/1 -> rows 0-7 / 8-15), 8 lanes per row.
  auto stage_tile = [&](unsigned short* dst, const unsigned short* srcbase,
                        int rowlen, int step, int half) {
    const int sr = (half << 3) + (lane >> 3);
    const int sc = lane & 7;
    const unsigned short* src = srcbase + ((size_t)(b0 + sr)*NT + step)*rowlen;
    const int nld = rowlen >> 6;        // 512 -> 8, 128 -> 2 (16B granules/lane)
    s16x8 tmp[8];
    #pragma unroll
    for (int i = 0; i < 8; ++i) if (i < nld) tmp[i] = *(const s16x8*)(src + (i*8 + sc)*8);
    #pragma unroll
    for (int i = 0; i < 8; ++i) if (i < nld) *(s16x8*)&dst[sr*HSTR + (i*8 + sc)*8] = tmp[i];
  };

  // ---- prologue ----
  if (!isrec) {
    // xp(0) computed directly from global -> xpL[0]
    if (l > 0 && lane < 4) poll4(line_prev, lane, 1u);
    asm volatile("" ::: "memory");
    f32x4 a0 = {0.f,0.f,0.f,0.f}, a1 = {0.f,0.f,0.f,0.f};
    const unsigned short* ar = (l==0)
        ? xbf  + (size_t)(b0+col)*NT*NF + quad*8
        : seqr + (size_t)(b0+col)*NT*NH + quad*8;
    #pragma unroll
    for (int kt = 0; kt < 16; ++kt) if (kt < KTx) {
      s16x8 a = *(const s16x8*)(ar + kt*32);
      a0 = __builtin_amdgcn_mfma_f32_16x16x32_bf16(a, wr0[kt], a0, 0, 0, 0);
      a1 = __builtin_amdgcn_mfma_f32_16x16x32_bf16(a, wr1[kt], a1, 0, 0, 0);
    }
    #pragma unroll
    for (int i = 0; i < 4; ++i) {
      int row = quad*4 + i;
      xpL[0][g][row][col]      = a0[i] + bias0;
      xpL[0][g][row][col + 16] = a1[i] + bias1;
    }
  } else if (wid < 2) {
    // stage xA with step-1 source (consumed by phase 1 of iter 0 -> xp(1))
    if (l > 0 && lane < 4) poll4(line_prev, lane, 2u);
    asm volatile("" ::: "memory");
    stage_tile(xA, (l==0) ? xbf : seqr, xrow, 1, wid);
  }
  __syncthreads();

  float hp0[4] = {0.f,0.f,0.f,0.f}, hp1[4] = {0.f,0.f,0.f,0.f};  // n-wave h state

  for (int t = 0; t < NT; ++t) {
    const int slot  = t & 1;
    const int nslot = slot ^ 1;

    f32x4 a0 = {0.f,0.f,0.f,0.f}, a1 = {0.f,0.f,0.f,0.f};

    // ---------------- phase 1: pure LDS -> MFMA compute ----------------
    if (isrec) {
      if (t > 0) {
        #pragma unroll
        for (int kt = 0; kt < 16; ++kt) {
          s16x8 a = *(const s16x8*)&hA[col*HSTR + kt*32 + quad*8];
          a0 = __builtin_amdgcn_mfma_f32_16x16x32_bf16(a, wr0[kt], a0, 0, 0, 0);
          a1 = __builtin_amdgcn_mfma_f32_16x16x32_bf16(a, wr1[kt], a1, 0, 0, 0);
        }
      }
      if (g < 2) {       // r/z: sigmoid -> LDS
        #pragma unroll
        for (int i = 0; i < 4; ++i) {
          int row = quad*4 + i;
          float p0 = a0[i] + xpL[slot][g][row][col]      + bias0;
          float p1 = a1[i] + xpL[slot][g][row][col + 16] + bias1;
          rzL[g][row][col]      = sigmoid_f(p0);
          rzL[g][row][col + 16] = sigmoid_f(p1);
        }
      } else {           // n: keep pre-activation hn (+bhh_n) in regs
        #pragma unroll
        for (int i = 0; i < 4; ++i) { a0[i] += bias0; a1[i] += bias1; }
      }
    } else if (t + 1 < NT) {   // xp waves: xp(t+1) from xA -> xpL[nslot]
      #pragma unroll
      for (int kt = 0; kt < 16; ++kt) if (kt < KTx) {
        s16x8 a = *(const s16x8*)&xA[col*HSTR + kt*32 + quad*8];
        a0 = __builtin_amdgcn_mfma_f32_16x16x32_bf16(a, wr0[kt], a0, 0, 0, 0);
        a1 = __builtin_amdgcn_mfma_f32_16x16x32_bf16(a, wr1[kt], a1, 0, 0, 0);
      }
      #pragma unroll
      for (int i = 0; i < 4; ++i) {
        int row = quad*4 + i;
        xpL[nslot][g][row][col]      = a0[i] + bias0;
        xpL[nslot][g][row][col + 16] = a1[i] + bias1;
      }
    }
    __syncthreads();   // B1

    // ---------------- phase 2: n-store  ||  poll+stage next tiles ----------
    if (wid == 2) {      // n-wave: gate combine, h update, sc1 store, flag
      #pragma unroll
      for (int i = 0; i < 4; ++i) {
        int row = quad*4 + i;
        float xn0 = xpL[slot][2][row][col];
        float xn1 = xpL[slot][2][row][col + 16];
        float rt0 = rzL[0][row][col],      rt1 = rzL[0][row][col + 16];
        float zt0 = rzL[1][row][col],      zt1 = rzL[1][row][col + 16];
        float nv0 = tanh_f(xn0 + rt0 * a0[i]);
        float nv1 = tanh_f(xn1 + rt1 * a1[i]);
        float h0 = (1.f - zt0)*nv0 + zt0*hp0[i];
        float h1 = (1.f - zt1)*nv1 + zt1*hp1[i];
        hp0[i] = h0; hp1[i] = h1;
        hout[row*32 + col]      = f2bf(h0);
        hout[row*32 + col + 16] = f2bf(h1);
      }
      asm volatile("s_waitcnt lgkmcnt(0)" ::: "memory");
      {
        int srow = lane >> 2, sch = lane & 3;
        s16x8 hv = *(const s16x8*)&hout[srow*32 + sch*8];
        unsigned short* p = seqw + ((size_t)(b0+srow)*NT + t)*NH + c0 + sch*8;
        asm volatile("global_store_dwordx4 %0, %1, off sc0 sc1" :: "v"(p), "v"(hv) : "memory");
        asm volatile("s_waitcnt vmcnt(0)" ::: "memory");   // h at coherence point
      }
      if (lane == 0)
        __hip_atomic_store(line_self + cq, (unsigned)(t + 1),
                           __ATOMIC_RELAXED, __HIP_MEMORY_SCOPE_AGENT);
    } else if (wid < 2) {        // stage hA = h(t) for phase 1 of t+1
      if (t + 1 < NT) {
        if (lane < 4) poll4(line_self, lane, (unsigned)(t + 1));
        asm volatile("" ::: "memory");
        stage_tile(hA, seqw, NH, t, wid);
      }
    } else if (wid == 3 || wid == 4) {   // stage xA = src(t+2) for xp(t+2)
      if (t + 2 < NT) {
        if (l > 0 && lane < 4) poll4(line_prev, lane, (unsigned)(t + 3));
        asm volatile("" ::: "memory");
        stage_tile(xA, (l==0) ? xbf : seqr, xrow, t + 2, wid - 3);
      }
    }
    __syncthreads();   // B2
  }
}

// ---------------- head GEMM: out[bt][o] = seq2[bt][:] . Wout[o][:] + bout ----
__global__ __launch_bounds__(256)
void head_gemm(const unsigned short* __restrict__ seq2,
               const unsigned short* __restrict__ woutb,
               const float* __restrict__ bout,
               float* __restrict__ out)
{
  int tid = threadIdx.x;
  int wv = tid >> 6, lane = tid & 63;
  int col = lane & 31, khi = lane >> 5;
  int id = blockIdx.x*4 + wv;
  int mt = id >> 2, nt = id & 3;
  int m0 = mt*32, n0 = nt*32;
  const unsigned short* arow = seq2  + (size_t)(m0 + col)*NH + (khi << 3);
  const unsigned short* brow = woutb + (size_t)(n0 + col)*NH + (khi << 3);
  f32x16 acc;
  #pragma unroll
  for (int i = 0; i < 16; ++i) acc[i] = 0.f;
  #pragma unroll 8
  for (int kt = 0; kt < 32; ++kt) {
    s16x8 a = *(const s16x8*)(arow + kt*16);
    s16x8 b = *(const s16x8*)(brow + kt*16);
    acc = __builtin_amdgcn_mfma_f32_32x32x16_bf16(a, b, acc, 0, 0, 0);
  }
  float bo = bout[n0 + col];
  #pragma unroll
  for (int r = 0; r < 16; ++r) {
    int row = (r & 3) + ((r >> 2) << 3) + (khi << 2);
    out[(size_t)(m0 + row)*NO + n0 + col] = acc[r] + bo;
  }
}

__global__ void cast_f32_bf16(const float* __restrict__ src,
                              unsigned short* __restrict__ dst, int n) {
  int i = blockIdx.x*blockDim.x + threadIdx.x;
  int stride = gridDim.x*blockDim.x;
  for (; i < n; i += stride) dst[i] = f2bf(src[i]);
}

extern "C" void kernel_launch(void* const* d_in, const int* in_sizes, int n_in,
                              void* d_out, int out_size, void* d_ws, size_t ws_size,
                              hipStream_t stream) {
  (void)in_sizes; (void)n_in; (void)out_size; (void)ws_size;
  const float* x    = (const float*)d_in[0];
  const float* Wih0 = (const float*)d_in[1];
  const float* Whh0 = (const float*)d_in[2];
  const float* bih0 = (const float*)d_in[3];
  const float* bhh0 = (const float*)d_in[4];
  const float* Wih1 = (const float*)d_in[5];
  const float* Whh1 = (const float*)d_in[6];
  const float* bih1 = (const float*)d_in[7];
  const float* bhh1 = (const float*)d_in[8];
  const float* Wih2 = (const float*)d_in[9];
  const float* Whh2 = (const float*)d_in[10];
  const float* bih2 = (const float*)d_in[11];
  const float* bhh2 = (const float*)d_in[12];
  const float* Wout = (const float*)d_in[13];
  const float* bout = (const float*)d_in[14];

  char* ws = (char*)d_ws;
  unsigned short* xbf  = (unsigned short*)(ws + OFF_XBF);
  unsigned short* wob  = (unsigned short*)(ws + OFF_WOUT);
  unsigned short* seq0 = (unsigned short*)(ws + OFF_SEQ0);
  unsigned short* seq1 = (unsigned short*)(ws + OFF_SEQ1);
  unsigned short* seq2 = (unsigned short*)(ws + OFF_SEQ2);
  unsigned int*   flg  = (unsigned int*)(ws + OFF_FLAGS);

  // allow >64KB dynamic LDS (idempotent, capture-safe)
  (void)hipFuncSetAttribute((const void*)gru_persist,
                            hipFuncAttributeMaxDynamicSharedMemorySize, 160*1024);

  hipMemsetAsync(ws + OFF_FLAGS, 0, 4096, stream);
  cast_f32_bf16<<<512, 256, 0, stream>>>(x, xbf, NB*NT*NF);
  cast_f32_bf16<<<64, 256, 0, stream>>>(Wout, wob, NO*NH);
  gru_persist<<<192, 384, SMEM_BYTES, stream>>>(xbf, seq0, seq1, seq2, flg,
      Wih0, Whh0, bih0, bhh0, Wih1, Whh1, bih1, bhh1, Wih2, Whh2, bih2, bhh2);
  head_gemm<<<1024, 256, 0, stream>>>(seq2, wob, bout, (float*)d_out);
}